// Round 15
// baseline (319.223 us; speedup 1.0000x reference)
//
#include <hip/hip_runtime.h>
#include <hip/hip_fp16.h>

constexpr int kN  = 50000;
constexpr int kE  = 400000;
constexpr int kHC = 128;
constexpr int kED = 32;
constexpr int kL  = 2;
constexpr int kScanB = (kN + 255) / 256;   // 196
constexpr int kProjBlocks = 512;           // persistent: 2 per CU
constexpr int kTiles = (kN + 31) / 32;     // 1563
#define EPS_LN 1e-5f
#define NEG_SLOPE 0.01f
#define RSQRT_C 0.17677669529663687f  // 1/sqrt(32)

using half8 = __attribute__((ext_vector_type(8))) _Float16;
using half4 = __attribute__((ext_vector_type(4))) _Float16;
using h2    = __attribute__((ext_vector_type(2))) _Float16;
using f32x4 = __attribute__((ext_vector_type(4))) float;

#if __has_builtin(__builtin_amdgcn_fdot2)
#define FDOT2(a, b, c) __builtin_amdgcn_fdot2((a), (b), (c), false)
#else
#define FDOT2(a, b, c) (fmaf((float)(a)[0], (float)(b)[0], \
                        fmaf((float)(a)[1], (float)(b)[1], (c))))
#endif

// ---------------- Weight transpose+convert: Wt[mat][n][k] fp16 --------------
__global__ __launch_bounds__(256) void wt_kernel(
    const float* __restrict__ Wq, const float* __restrict__ Wk,
    const float* __restrict__ Wv, const float* __restrict__ Ws,
    _Float16* __restrict__ Wt)
{
    const int g = blockIdx.x * 256 + threadIdx.x;   // 8192 total
    const int n  = g & 127;
    const int kc = (g >> 7) & 15;
    const int mat = g >> 11;
    const float* W = mat == 0 ? Wq : mat == 1 ? Wk : mat == 2 ? Wv : Ws;
    _Float16* dst = Wt + ((size_t)mat * 128 + n) * 128 + kc * 8;
#pragma unroll
    for (int i = 0; i < 8; i++) dst[i] = (_Float16)W[(kc * 8 + i) * kHC + n];
}

// ---------------- We -> fp16 copy (once per layer) --------------------------
__global__ __launch_bounds__(256) void we16_kernel(
    const float* __restrict__ We, _Float16* __restrict__ We16)
{
    const int g = blockIdx.x * 256 + threadIdx.x;   // 4096
    if (g < kED * kHC) We16[g] = (_Float16)We[g];
}

// ---------------- Persistent MFMA projection --------------------------------
// outputs: q16 [n][128], kv16 [n][256] channel-interleaved {k0,k1,v0,v1}, xr16
template<bool FP16IN>
__global__ __launch_bounds__(256, 2) void proj_mfma_kernel(
    const void* __restrict__ hin_, const _Float16* __restrict__ Wt,
    const float* __restrict__ bq, const float* __restrict__ bk,
    const float* __restrict__ bv, const float* __restrict__ bs,
    _Float16* __restrict__ q16, _Float16* __restrict__ kv16,
    _Float16* __restrict__ xr16)
{
    __shared__ _Float16 lds_a[4096];          // [mt][ks][lane][8] frag-linear
    __shared__ _Float16 lds_o[4][32 * 132];   // repack staging, stride 132
    const int t = threadIdx.x;
    const int w = t >> 6;        // wave id = matrix id (0:q 1:k 2:v 3:skip)
    const int lane = t & 63;
    const int nrow = lane & 15;
    const int kc4  = (lane >> 4) * 4;

    half8 bf[32];
    {
        const _Float16* wtm = Wt + (size_t)w * 128 * 128;
#pragma unroll
        for (int ks = 0; ks < 4; ks++)
#pragma unroll
            for (int nt = 0; nt < 8; nt++)
                bf[ks * 8 + nt] = *(const half8*)
                    &wtm[(size_t)(nt * 16 + nrow) * 128 + ks * 32 + (lane >> 4) * 8];
    }

    const int sr  = t >> 3;
    const int sk0 = (t & 7) * 16;
    const int smt = sr >> 4;
    const int sl15 = sr & 15;

    float4 f[4];
    half8 hh[2];

    auto stage_to_regs = [&](int tile) {
        const int row = tile * 32 + sr;
        if (row < kN) {
            if constexpr (FP16IN) {
                const _Float16* src = (const _Float16*)hin_ + (size_t)row * kHC + sk0;
                hh[0] = *(const half8*)&src[0];
                hh[1] = *(const half8*)&src[8];
            } else {
                const float4* src = (const float4*)((const float*)hin_ + (size_t)row * kHC + sk0);
                f[0] = src[0]; f[1] = src[1]; f[2] = src[2]; f[3] = src[3];
            }
        } else {
            if constexpr (FP16IN) {
                hh[0] = half8{0, 0, 0, 0, 0, 0, 0, 0};
                hh[1] = half8{0, 0, 0, 0, 0, 0, 0, 0};
            } else {
                f[0] = f[1] = f[2] = f[3] = make_float4(0.f, 0.f, 0.f, 0.f);
            }
        }
    };

    auto regs_to_lds = [&]() {
        half8 h0, h1;
        if constexpr (FP16IN) {
            h0 = hh[0]; h1 = hh[1];
        } else {
            h0[0] = (_Float16)f[0].x; h0[1] = (_Float16)f[0].y;
            h0[2] = (_Float16)f[0].z; h0[3] = (_Float16)f[0].w;
            h0[4] = (_Float16)f[1].x; h0[5] = (_Float16)f[1].y;
            h0[6] = (_Float16)f[1].z; h0[7] = (_Float16)f[1].w;
            h1[0] = (_Float16)f[2].x; h1[1] = (_Float16)f[2].y;
            h1[2] = (_Float16)f[2].z; h1[3] = (_Float16)f[2].w;
            h1[4] = (_Float16)f[3].x; h1[5] = (_Float16)f[3].y;
            h1[6] = (_Float16)f[3].z; h1[7] = (_Float16)f[3].w;
        }
#pragma unroll
        for (int g = 0; g < 2; g++) {
            const int k  = sk0 + g * 8;
            const int ks = k >> 5;
            const int kc = (k >> 3) & 3;
            *(half8*)&lds_a[(((smt * 4 + ks) * 64) + kc * 16 + sl15) * 8] = g ? h1 : h0;
        }
    };

    const float* biasp = (w == 0) ? bq : (w == 1) ? bk : (w == 2) ? bv : bs;
    float bb[8];
#pragma unroll
    for (int nt = 0; nt < 8; nt++) bb[nt] = biasp[nt * 16 + nrow];

    int tile = blockIdx.x;
    stage_to_regs(tile);

    for (;;) {
        __syncthreads();
        regs_to_lds();
        __syncthreads();

        const int next = tile + kProjBlocks;
        const bool more = next < kTiles;
        if (more) stage_to_regs(next);

        f32x4 acc[2][8];
        const f32x4 z = {0.f, 0.f, 0.f, 0.f};
#pragma unroll
        for (int mt = 0; mt < 2; mt++)
#pragma unroll
            for (int nt = 0; nt < 8; nt++) acc[mt][nt] = z;

#pragma unroll
        for (int ks = 0; ks < 4; ks++) {
            const half8 a0 = *(const half8*)&lds_a[((0 * 4 + ks) * 64 + lane) * 8];
            const half8 a1 = *(const half8*)&lds_a[((1 * 4 + ks) * 64 + lane) * 8];
#pragma unroll
            for (int nt = 0; nt < 8; nt++) {
                acc[0][nt] = __builtin_amdgcn_mfma_f32_16x16x32_f16(a0, bf[ks * 8 + nt], acc[0][nt], 0, 0, 0);
                acc[1][nt] = __builtin_amdgcn_mfma_f32_16x16x32_f16(a1, bf[ks * 8 + nt], acc[1][nt], 0, 0, 0);
            }
        }

#pragma unroll
        for (int nt = 0; nt < 8; nt++) {
#pragma unroll
            for (int mt = 0; mt < 2; mt++)
#pragma unroll
                for (int r = 0; r < 4; r++)
                    lds_o[w][(mt * 16 + kc4 + r) * 132 + nt * 16 + nrow] =
                        (_Float16)(acc[mt][nt][r] + bb[nt]);
        }
        __syncthreads();

        // copy-out: q, kv channel-interleaved, xr
        const int grow = tile * 32 + sr;
        if (grow < kN) {
            {   // q
                const _Float16* s = &lds_o[0][sr * 132 + sk0];
                _Float16* d = q16 + (size_t)grow * kHC + sk0;
#pragma unroll
                for (int i = 0; i < 4; i++)
                    *(half4*)&d[i * 4] = *(const half4*)&s[i * 4];
            }
            {   // kv interleaved: {k0,k1,v0,v1} per channel pair
                const _Float16* sk = &lds_o[1][sr * 132 + sk0];
                const _Float16* sv = &lds_o[2][sr * 132 + sk0];
                _Float16* d = kv16 + (size_t)grow * 256 + sk0 * 2;
#pragma unroll
                for (int i = 0; i < 4; i++) {
                    const half4 kk = *(const half4*)&sk[i * 4];
                    const half4 vv = *(const half4*)&sv[i * 4];
                    half4 o0, o1;
                    o0[0] = kk[0]; o0[1] = kk[1]; o0[2] = vv[0]; o0[3] = vv[1];
                    o1[0] = kk[2]; o1[1] = kk[3]; o1[2] = vv[2]; o1[3] = vv[3];
                    *(half4*)&d[i * 8]     = o0;
                    *(half4*)&d[i * 8 + 4] = o1;
                }
            }
            {   // xr
                const _Float16* s = &lds_o[3][sr * 132 + sk0];
                _Float16* d = xr16 + (size_t)grow * kHC + sk0;
#pragma unroll
                for (int i = 0; i < 4; i++)
                    *(half4*)&d[i * 4] = *(const half4*)&s[i * 4];
            }
        }

        if (!more) break;
        tile = next;
    }
}

// ---------------- qeW: register-blocked, 32 nodes per block -----------------
constexpr int kQewNPB = 32;
__global__ __launch_bounds__(256) void qew_kernel(
    const __half* __restrict__ q16, const float* __restrict__ We,
    __half* __restrict__ qeW)
{
    const int t = threadIdx.x;
    const int o = t & 127;       // output index = h*32 + j
    const int h = o >> 5;
    const int j = o & 31;
    const int nd = t >> 7;

    float we[32];
    const float2* wrow = (const float2*)&We[j * kHC + h * 32];
#pragma unroll
    for (int i = 0; i < 16; i++) {
        const float2 w = wrow[i];
        we[2 * i] = w.x; we[2 * i + 1] = w.y;
    }

    const int n0 = blockIdx.x * kQewNPB;
    for (int i = nd; i < kQewNPB; i += 2) {
        const int n = n0 + i;
        if (n >= kN) break;
        const __half2* qrow = (const __half2*)&q16[(size_t)n * kHC + h * 32];
        float s = 0.f;
#pragma unroll
        for (int ii = 0; ii < 16; ii++) {
            const float2 qf = __half22float2(qrow[ii]);
            s = fmaf(qf.x, we[2 * ii], s);
            s = fmaf(qf.y, we[2 * ii + 1], s);
        }
        qeW[(size_t)n * kHC + o] = __float2half(s);
    }
}

// ---------------- qb[n,h] = sum_{c in h} q[n,c]*be[c] -----------------------
__global__ __launch_bounds__(256) void qb_kernel(
    const __half* __restrict__ q16, const float* __restrict__ be,
    float* __restrict__ qb)
{
    const int g = blockIdx.x * 256 + threadIdx.x;   // n*4 + h
    if (g >= kN * 4) return;
    const int n = g >> 2, h = g & 3;
    const __half2* qrow = (const __half2*)&q16[(size_t)n * kHC + h * 32];
    const float2* brow = (const float2*)&be[h * 32];
    float s = 0.f;
#pragma unroll
    for (int i = 0; i < 16; i++) {
        const float2 qf = __half22float2(qrow[i]);
        const float2 bf = brow[i];
        s = fmaf(qf.x, bf.x, s);
        s = fmaf(qf.y, bf.y, s);
    }
    qb[g] = s;
}

// ---------------- CSR build (once per call) ---------------------------------
__global__ __launch_bounds__(256) void hist_kernel(
    const int* __restrict__ dstI, int* __restrict__ deg)
{
    const int e = blockIdx.x * 256 + threadIdx.x;
    if (e < kE) atomicAdd(&deg[dstI[e]], 1);
}

__global__ __launch_bounds__(256) void scanA_kernel(
    const int* __restrict__ deg, int* __restrict__ locInc, int* __restrict__ blockSum)
{
    __shared__ int sm[256];
    const int t = threadIdx.x;
    const int i = blockIdx.x * 256 + t;
    sm[t] = (i < kN) ? deg[i] : 0;
    __syncthreads();
    for (int off = 1; off < 256; off <<= 1) {
        const int x = (t >= off) ? sm[t - off] : 0;
        __syncthreads();
        sm[t] += x;
        __syncthreads();
    }
    if (i < kN) locInc[i] = sm[t];
    if (t == 255) blockSum[blockIdx.x] = sm[255];
}

__global__ __launch_bounds__(256) void scanC_kernel(
    const int* __restrict__ deg, const int* __restrict__ locInc,
    const int* __restrict__ blockSum,
    int* __restrict__ rowptr, int* __restrict__ cursor)
{
    __shared__ int sm[256];
    const int t = threadIdx.x;
    const int b = blockIdx.x;
    sm[t] = (t < b) ? blockSum[t] : 0;   // b <= 195 < 256
    __syncthreads();
    for (int s = 128; s > 0; s >>= 1) {
        if (t < s) sm[t] += sm[t + s];
        __syncthreads();
    }
    const int off = sm[0];
    const int i = b * 256 + t;
    if (i < kN) {
        const int inc = locInc[i];
        const int excl = off + inc - deg[i];
        rowptr[i] = excl;
        cursor[i] = excl;
        if (i == kN - 1) rowptr[kN] = off + inc;
    }
}

__global__ __launch_bounds__(256) void scatter_kernel(
    const int* __restrict__ srcI, const int* __restrict__ dstI,
    int* __restrict__ cursor, int* __restrict__ esrc, int* __restrict__ eidx)
{
    const int e = blockIdx.x * 256 + threadIdx.x;
    if (e >= kE) return;
    const int d = dstI[e];
    const int pos = atomicAdd(&cursor[d], 1);
    esrc[pos] = srcI[e];
    eidx[pos] = e;
}

// ---------------- ea -> CSR-order fp16 copy (once per call) -----------------
__global__ __launch_bounds__(256) void ea_csr_kernel(
    const float* __restrict__ ea, const int* __restrict__ eidx,
    __half* __restrict__ eacsr)
{
    const int g = blockIdx.x * 256 + threadIdx.x;   // kE*16 threads
    if (g >= kE * 16) return;
    const int jj = g >> 4;
    const int li = g & 15;
    const int eid = eidx[jj];
    const float2 ea2 = *(const float2*)&ea[(size_t)eid * kED + 2 * li];
    *(__half2*)&eacsr[(size_t)jj * kED + 2 * li] = __floats2half2_rn(ea2.x, ea2.y);
}

// ---------------- Fused node pass: logits + softmax + agg + epilogue --------
template<bool LAST>
__global__ __launch_bounds__(256) void node_kernel(
    const _Float16* __restrict__ q16, const __half* __restrict__ qeW,
    const float* __restrict__ qb, const _Float16* __restrict__ eacsr,
    const _Float16* __restrict__ kv16,
    const int* __restrict__ rowptr, const int* __restrict__ esrc,
    const _Float16* __restrict__ We16, const float* __restrict__ be,
    const __half* __restrict__ xr16, const float* __restrict__ Wb,
    const float* __restrict__ lnw, const float* __restrict__ lnb,
    void* __restrict__ hout)
{
    __shared__ __half wes[kED * kHC];   // 8 KB
    const int t = threadIdx.x;
    {
        float4* d4 = (float4*)wes;
        const float4* s4 = (const float4*)We16;
        d4[t] = s4[t];
        d4[t + 256] = s4[t + 256];
    }
    __syncthreads();

    const int n = blockIdx.x * 4 + (t >> 6);   // kN % 4 == 0
    const int lane = t & 63;
    const int c = lane << 1;
    const int li = lane & 15;
    const int h = lane >> 4;

    // loop-invariant per node (half2 regs for dot2)
    const h2 qh  = *(const h2*)&q16[n * kHC + c];
    const h2 qwh = *(const h2*)((const _Float16*)qeW + n * kHC + c);
    const float qbv = qb[n * 4 + h];

    float acc0 = 0.f, acc1 = 0.f, t0 = 0.f, t1 = 0.f, den = 0.f;
    const int beg = rowptr[n], endp = rowptr[n + 1];
    const int lane4 = lane << 2;
    const _Float16* eap = eacsr + beg * kED + 2 * li;

    int jj = beg;
    for (; jj + 2 <= endp; jj += 2, eap += 2 * kED) {
        const int s0 = esrc[jj];
        const int s1 = esrc[jj + 1];
        const half4 kv0 = *(const half4*)(kv16 + s0 * 256 + lane4);
        const half4 kv1 = *(const half4*)(kv16 + s1 * 256 + lane4);
        const h2 ea0 = *(const h2*)eap;
        const h2 ea1 = *(const h2*)(eap + kED);
        const h2 k0 = __builtin_shufflevector(kv0, kv0, 0, 1);
        const h2 k1 = __builtin_shufflevector(kv1, kv1, 0, 1);
        float p0 = FDOT2(qh, k0, 0.f);
        float p1 = FDOT2(qh, k1, 0.f);
        p0 = FDOT2(qwh, ea0, p0);
        p1 = FDOT2(qwh, ea1, p1);
        p0 += __shfl_xor(p0, 1);  p1 += __shfl_xor(p1, 1);
        p0 += __shfl_xor(p0, 2);  p1 += __shfl_xor(p1, 2);
        p0 += __shfl_xor(p0, 4);  p1 += __shfl_xor(p1, 4);
        p0 += __shfl_xor(p0, 8);  p1 += __shfl_xor(p1, 8);
        const float a0 = __expf((p0 + qbv) * RSQRT_C);
        const float a1 = __expf((p1 + qbv) * RSQRT_C);
        den += a0 + a1;
        acc0 = fmaf((float)kv0[2], a0, acc0); acc0 = fmaf((float)kv1[2], a1, acc0);
        acc1 = fmaf((float)kv0[3], a0, acc1); acc1 = fmaf((float)kv1[3], a1, acc1);
        t0 = fmaf((float)ea0[0], a0, t0); t0 = fmaf((float)ea1[0], a1, t0);
        t1 = fmaf((float)ea0[1], a0, t1); t1 = fmaf((float)ea1[1], a1, t1);
    }
    if (jj < endp) {
        const int s0 = esrc[jj];
        const half4 kv0 = *(const half4*)(kv16 + s0 * 256 + lane4);
        const h2 ea0 = *(const h2*)eap;
        const h2 k0 = __builtin_shufflevector(kv0, kv0, 0, 1);
        float p0 = FDOT2(qh, k0, 0.f);
        p0 = FDOT2(qwh, ea0, p0);
        p0 += __shfl_xor(p0, 1);
        p0 += __shfl_xor(p0, 2);
        p0 += __shfl_xor(p0, 4);
        p0 += __shfl_xor(p0, 8);
        const float a0 = __expf((p0 + qbv) * RSQRT_C);
        den += a0;
        acc0 = fmaf((float)kv0[2], a0, acc0);
        acc1 = fmaf((float)kv0[3], a0, acc1);
        t0 = fmaf((float)ea0[0], a0, t0);
        t1 = fmaf((float)ea0[1], a0, t1);
    }
    const float invd = 1.f / (den + 1e-16f);
    float o0 = acc0 * invd;
    float o1 = acc1 * invd;
    const float tn0 = t0 * invd, tn1 = t1 * invd;
    const int gbase = lane & 48;
#pragma unroll
    for (int i = 0; i < 16; i++) {
        const float Ta = __shfl(tn0, gbase | i);
        const float Tb = __shfl(tn1, gbase | i);
        const float2 wa = __half22float2(*(const __half2*)&wes[(2 * i) * kHC + c]);
        const float2 wb = __half22float2(*(const __half2*)&wes[(2 * i + 1) * kHC + c]);
        o0 = fmaf(Ta, wa.x, o0); o1 = fmaf(Ta, wa.y, o1);
        o0 = fmaf(Tb, wb.x, o0); o1 = fmaf(Tb, wb.y, o1);
    }
    o0 += be[c];
    o1 += be[c + 1];

    const float2 r = __half22float2(*(const __half2*)&xr16[(size_t)n * kHC + c]);
    float z = o0 * Wb[c] + o1 * Wb[c + 1]
            + r.x * Wb[kHC + c] + r.y * Wb[kHC + c + 1]
            + (o0 - r.x) * Wb[2 * kHC + c] + (o1 - r.y) * Wb[2 * kHC + c + 1];
#pragma unroll
    for (int m = 1; m < 64; m <<= 1) z += __shfl_xor(z, m);
    const float beta = 1.f / (1.f + __expf(-z));

    const float g0 = beta * r.x + (1.f - beta) * o0;
    const float g1 = beta * r.y + (1.f - beta) * o1;

    float sm = g0 + g1;
    float sq = g0 * g0 + g1 * g1;
#pragma unroll
    for (int m = 1; m < 64; m <<= 1) {
        sm += __shfl_xor(sm, m);
        sq += __shfl_xor(sq, m);
    }
    const float mu  = sm * (1.f / kHC);
    const float var = sq * (1.f / kHC) - mu * mu;
    const float inv = rsqrtf(var + EPS_LN);

    float y0 = (g0 - mu) * inv * lnw[c] + lnb[c];
    float y1 = (g1 - mu) * inv * lnw[c + 1] + lnb[c + 1];
    y0 = y0 > 0.f ? y0 : NEG_SLOPE * y0;
    y1 = y1 > 0.f ? y1 : NEG_SLOPE * y1;
    if constexpr (LAST) {
        *(float2*)&((float*)hout)[(size_t)n * kHC + c] = make_float2(y0, y1);
    } else {
        *(__half2*)&((__half*)hout)[(size_t)n * kHC + c] = __floats2half2_rn(y0, y1);
    }
}

extern "C" void kernel_launch(void* const* d_in, const int* in_sizes, int n_in,
                              void* d_out, int out_size, void* d_ws, size_t ws_size,
                              hipStream_t stream)
{
    const float* x   = (const float*)d_in[0];
    const int*   ei  = (const int*)d_in[1];
    const float* ea  = (const float*)d_in[2];
    const float* Wq  = (const float*)d_in[3];
    const float* bq  = (const float*)d_in[4];
    const float* Wk  = (const float*)d_in[5];
    const float* bk  = (const float*)d_in[6];
    const float* Wv  = (const float*)d_in[7];
    const float* bv  = (const float*)d_in[8];
    const float* We  = (const float*)d_in[9];
    const float* be  = (const float*)d_in[10];
    const float* Wsk = (const float*)d_in[11];
    const float* bsk = (const float*)d_in[12];
    const float* Wb  = (const float*)d_in[13];
    const float* lnw = (const float*)d_in[14];
    const float* lnb = (const float*)d_in[15];
    float* out = (float*)d_out;

    const int* srcI = ei;
    const int* dstI = ei + kE;

    // ---- workspace layout (~100 MB) ----
    __half* q16  = (__half*)d_ws;
    __half* kv16 = q16 + (size_t)kN * kHC;              // [n][256] interleaved
    __half* qeW  = kv16 + (size_t)kN * 256;
    __half* xr16 = qeW + (size_t)kN * kHC;
    __half* h16  = xr16 + (size_t)kN * kHC;
    float*  qb   = (float*)(h16 + (size_t)kN * kHC);
    int* deg     = (int*)(qb + (size_t)kN * 4);
    int* rowptr  = deg + kN;
    int* cursor  = rowptr + kN + 1;
    int* esrc    = cursor + kN;
    int* eidx    = esrc + kE;
    __half* eacs = (__half*)(eidx + kE);
    _Float16* Wt = (_Float16*)(eacs + (size_t)kE * kED);   // 128 KB
    _Float16* We16 = Wt + 4 * 128 * 128;                   // 8 KB
    int* locInc  = (int*)(We16 + kED * kHC);
    int* blockSum = locInc + kN;

    // ---- CSR build (edge_index constant across layers) ----
    hipMemsetAsync(deg, 0, (size_t)kN * sizeof(int), stream);
    hist_kernel<<<(kE + 255) / 256, 256, 0, stream>>>(dstI, deg);
    scanA_kernel<<<kScanB, 256, 0, stream>>>(deg, locInc, blockSum);
    scanC_kernel<<<kScanB, 256, 0, stream>>>(deg, locInc, blockSum, rowptr, cursor);
    scatter_kernel<<<(kE + 255) / 256, 256, 0, stream>>>(srcI, dstI, cursor, esrc, eidx);
    ea_csr_kernel<<<(kE * 16 + 255) / 256, 256, 0, stream>>>(ea, eidx, eacs);

    for (int l = 0; l < kL; l++) {
        wt_kernel<<<32, 256, 0, stream>>>(
            Wq + (size_t)l * kHC * kHC, Wk + (size_t)l * kHC * kHC,
            Wv + (size_t)l * kHC * kHC, Wsk + (size_t)l * kHC * kHC, Wt);
        we16_kernel<<<16, 256, 0, stream>>>(We + (size_t)l * kHC * kED, We16);
        if (l == 0)
            proj_mfma_kernel<false><<<kProjBlocks, 256, 0, stream>>>(
                x, Wt,
                bq + (size_t)l * kHC, bk + (size_t)l * kHC,
                bv + (size_t)l * kHC, bsk + (size_t)l * kHC,
                (_Float16*)q16, (_Float16*)kv16, (_Float16*)xr16);
        else
            proj_mfma_kernel<true><<<kProjBlocks, 256, 0, stream>>>(
                h16, Wt,
                bq + (size_t)l * kHC, bk + (size_t)l * kHC,
                bv + (size_t)l * kHC, bsk + (size_t)l * kHC,
                (_Float16*)q16, (_Float16*)kv16, (_Float16*)xr16);
        qew_kernel<<<(kN + kQewNPB - 1) / kQewNPB, 256, 0, stream>>>(
            q16, We + (size_t)l * kED * kHC, qeW);
        qb_kernel<<<(kN * 4 + 255) / 256, 256, 0, stream>>>(
            q16, be + (size_t)l * kHC, qb);
        if (l == 0)
            node_kernel<false><<<kN / 4, 256, 0, stream>>>(
                (const _Float16*)q16, qeW, qb, (const _Float16*)eacs,
                (const _Float16*)kv16, rowptr, esrc,
                We16, be + (size_t)l * kHC,
                xr16, Wb + (size_t)l * 3 * kHC,
                lnw + (size_t)l * kHC, lnb + (size_t)l * kHC,
                h16);
        else
            node_kernel<true><<<kN / 4, 256, 0, stream>>>(
                (const _Float16*)q16, qeW, qb, (const _Float16*)eacs,
                (const _Float16*)kv16, rowptr, esrc,
                We16, be + (size_t)l * kHC,
                xr16, Wb + (size_t)l * 3 * kHC,
                lnw + (size_t)l * kHC, lnb + (size_t)l * kHC,
                out);
    }
}

// Round 16
// 314.597 us; speedup vs baseline: 1.0147x; 1.0147x over previous
//
#include <hip/hip_runtime.h>
#include <hip/hip_fp16.h>

constexpr int kN  = 50000;
constexpr int kE  = 400000;
constexpr int kHC = 128;
constexpr int kED = 32;
constexpr int kL  = 2;
constexpr int kScanB = (kN + 255) / 256;   // 196
constexpr int kProjBlocks = 512;           // persistent: 2 per CU
constexpr int kTiles = (kN + 31) / 32;     // 1563
#define EPS_LN 1e-5f
#define NEG_SLOPE 0.01f
#define RSQRT_C 0.17677669529663687f  // 1/sqrt(32)

using half8 = __attribute__((ext_vector_type(8))) _Float16;
using half4 = __attribute__((ext_vector_type(4))) _Float16;
using h2    = __attribute__((ext_vector_type(2))) _Float16;
using f32x4 = __attribute__((ext_vector_type(4))) float;

#if __has_builtin(__builtin_amdgcn_fdot2)
#define FDOT2(a, b, c) __builtin_amdgcn_fdot2((a), (b), (c), false)
#else
#define FDOT2(a, b, c) (fmaf((float)(a)[0], (float)(b)[0], \
                        fmaf((float)(a)[1], (float)(b)[1], (c))))
#endif

// ---------------- Weight transpose+convert: Wt[mat][n][k] fp16 --------------
__global__ __launch_bounds__(256) void wt_kernel(
    const float* __restrict__ Wq, const float* __restrict__ Wk,
    const float* __restrict__ Wv, const float* __restrict__ Ws,
    _Float16* __restrict__ Wt)
{
    const int g = blockIdx.x * 256 + threadIdx.x;   // 8192 total
    const int n  = g & 127;
    const int kc = (g >> 7) & 15;
    const int mat = g >> 11;
    const float* W = mat == 0 ? Wq : mat == 1 ? Wk : mat == 2 ? Wv : Ws;
    _Float16* dst = Wt + ((size_t)mat * 128 + n) * 128 + kc * 8;
#pragma unroll
    for (int i = 0; i < 8; i++) dst[i] = (_Float16)W[(kc * 8 + i) * kHC + n];
}

// ---------------- We -> fp16 copy (once per layer) --------------------------
__global__ __launch_bounds__(256) void we16_kernel(
    const float* __restrict__ We, _Float16* __restrict__ We16)
{
    const int g = blockIdx.x * 256 + threadIdx.x;   // 4096
    if (g < kED * kHC) We16[g] = (_Float16)We[g];
}

// ---------------- Persistent MFMA projection --------------------------------
// outputs: q16 [n][128], kv16 [n][256] channel-interleaved {k0,k1,v0,v1}, xr16
template<bool FP16IN>
__global__ __launch_bounds__(256, 2) void proj_mfma_kernel(
    const void* __restrict__ hin_, const _Float16* __restrict__ Wt,
    const float* __restrict__ bq, const float* __restrict__ bk,
    const float* __restrict__ bv, const float* __restrict__ bs,
    _Float16* __restrict__ q16, _Float16* __restrict__ kv16,
    _Float16* __restrict__ xr16)
{
    __shared__ _Float16 lds_a[4096];          // [mt][ks][lane][8] frag-linear
    __shared__ _Float16 lds_o[4][32 * 132];   // repack staging, stride 132
    const int t = threadIdx.x;
    const int w = t >> 6;        // wave id = matrix id (0:q 1:k 2:v 3:skip)
    const int lane = t & 63;
    const int nrow = lane & 15;
    const int kc4  = (lane >> 4) * 4;

    half8 bf[32];
    {
        const _Float16* wtm = Wt + (size_t)w * 128 * 128;
#pragma unroll
        for (int ks = 0; ks < 4; ks++)
#pragma unroll
            for (int nt = 0; nt < 8; nt++)
                bf[ks * 8 + nt] = *(const half8*)
                    &wtm[(size_t)(nt * 16 + nrow) * 128 + ks * 32 + (lane >> 4) * 8];
    }

    const int sr  = t >> 3;
    const int sk0 = (t & 7) * 16;
    const int smt = sr >> 4;
    const int sl15 = sr & 15;

    float4 f[4];
    half8 hh[2];

    auto stage_to_regs = [&](int tile) {
        const int row = tile * 32 + sr;
        if (row < kN) {
            if constexpr (FP16IN) {
                const _Float16* src = (const _Float16*)hin_ + (size_t)row * kHC + sk0;
                hh[0] = *(const half8*)&src[0];
                hh[1] = *(const half8*)&src[8];
            } else {
                const float4* src = (const float4*)((const float*)hin_ + (size_t)row * kHC + sk0);
                f[0] = src[0]; f[1] = src[1]; f[2] = src[2]; f[3] = src[3];
            }
        } else {
            if constexpr (FP16IN) {
                hh[0] = half8{0, 0, 0, 0, 0, 0, 0, 0};
                hh[1] = half8{0, 0, 0, 0, 0, 0, 0, 0};
            } else {
                f[0] = f[1] = f[2] = f[3] = make_float4(0.f, 0.f, 0.f, 0.f);
            }
        }
    };

    auto regs_to_lds = [&]() {
        half8 h0, h1;
        if constexpr (FP16IN) {
            h0 = hh[0]; h1 = hh[1];
        } else {
            h0[0] = (_Float16)f[0].x; h0[1] = (_Float16)f[0].y;
            h0[2] = (_Float16)f[0].z; h0[3] = (_Float16)f[0].w;
            h0[4] = (_Float16)f[1].x; h0[5] = (_Float16)f[1].y;
            h0[6] = (_Float16)f[1].z; h0[7] = (_Float16)f[1].w;
            h1[0] = (_Float16)f[2].x; h1[1] = (_Float16)f[2].y;
            h1[2] = (_Float16)f[2].z; h1[3] = (_Float16)f[2].w;
            h1[4] = (_Float16)f[3].x; h1[5] = (_Float16)f[3].y;
            h1[6] = (_Float16)f[3].z; h1[7] = (_Float16)f[3].w;
        }
#pragma unroll
        for (int g = 0; g < 2; g++) {
            const int k  = sk0 + g * 8;
            const int ks = k >> 5;
            const int kc = (k >> 3) & 3;
            *(half8*)&lds_a[(((smt * 4 + ks) * 64) + kc * 16 + sl15) * 8] = g ? h1 : h0;
        }
    };

    const float* biasp = (w == 0) ? bq : (w == 1) ? bk : (w == 2) ? bv : bs;
    float bb[8];
#pragma unroll
    for (int nt = 0; nt < 8; nt++) bb[nt] = biasp[nt * 16 + nrow];

    int tile = blockIdx.x;
    stage_to_regs(tile);

    for (;;) {
        __syncthreads();
        regs_to_lds();
        __syncthreads();

        const int next = tile + kProjBlocks;
        const bool more = next < kTiles;
        if (more) stage_to_regs(next);

        f32x4 acc[2][8];
        const f32x4 z = {0.f, 0.f, 0.f, 0.f};
#pragma unroll
        for (int mt = 0; mt < 2; mt++)
#pragma unroll
            for (int nt = 0; nt < 8; nt++) acc[mt][nt] = z;

#pragma unroll
        for (int ks = 0; ks < 4; ks++) {
            const half8 a0 = *(const half8*)&lds_a[((0 * 4 + ks) * 64 + lane) * 8];
            const half8 a1 = *(const half8*)&lds_a[((1 * 4 + ks) * 64 + lane) * 8];
#pragma unroll
            for (int nt = 0; nt < 8; nt++) {
                acc[0][nt] = __builtin_amdgcn_mfma_f32_16x16x32_f16(a0, bf[ks * 8 + nt], acc[0][nt], 0, 0, 0);
                acc[1][nt] = __builtin_amdgcn_mfma_f32_16x16x32_f16(a1, bf[ks * 8 + nt], acc[1][nt], 0, 0, 0);
            }
        }

#pragma unroll
        for (int nt = 0; nt < 8; nt++) {
#pragma unroll
            for (int mt = 0; mt < 2; mt++)
#pragma unroll
                for (int r = 0; r < 4; r++)
                    lds_o[w][(mt * 16 + kc4 + r) * 132 + nt * 16 + nrow] =
                        (_Float16)(acc[mt][nt][r] + bb[nt]);
        }
        __syncthreads();

        const int grow = tile * 32 + sr;
        if (grow < kN) {
            {   // q
                const _Float16* s = &lds_o[0][sr * 132 + sk0];
                _Float16* d = q16 + (size_t)grow * kHC + sk0;
#pragma unroll
                for (int i = 0; i < 4; i++)
                    *(half4*)&d[i * 4] = *(const half4*)&s[i * 4];
            }
            {   // kv interleaved: {k0,k1,v0,v1} per channel pair
                const _Float16* sk = &lds_o[1][sr * 132 + sk0];
                const _Float16* sv = &lds_o[2][sr * 132 + sk0];
                _Float16* d = kv16 + (size_t)grow * 256 + sk0 * 2;
#pragma unroll
                for (int i = 0; i < 4; i++) {
                    const half4 kk = *(const half4*)&sk[i * 4];
                    const half4 vv = *(const half4*)&sv[i * 4];
                    half4 o0, o1;
                    o0[0] = kk[0]; o0[1] = kk[1]; o0[2] = vv[0]; o0[3] = vv[1];
                    o1[0] = kk[2]; o1[1] = kk[3]; o1[2] = vv[2]; o1[3] = vv[3];
                    *(half4*)&d[i * 8]     = o0;
                    *(half4*)&d[i * 8 + 4] = o1;
                }
            }
            {   // xr
                const _Float16* s = &lds_o[3][sr * 132 + sk0];
                _Float16* d = xr16 + (size_t)grow * kHC + sk0;
#pragma unroll
                for (int i = 0; i < 4; i++)
                    *(half4*)&d[i * 4] = *(const half4*)&s[i * 4];
            }
        }

        if (!more) break;
        tile = next;
    }
}

// ---------------- qeW: register-blocked, 32 nodes per block -----------------
constexpr int kQewNPB = 32;
__global__ __launch_bounds__(256) void qew_kernel(
    const __half* __restrict__ q16, const float* __restrict__ We,
    __half* __restrict__ qeW)
{
    const int t = threadIdx.x;
    const int o = t & 127;       // output index = h*32 + j
    const int h = o >> 5;
    const int j = o & 31;
    const int nd = t >> 7;

    float we[32];
    const float2* wrow = (const float2*)&We[j * kHC + h * 32];
#pragma unroll
    for (int i = 0; i < 16; i++) {
        const float2 w = wrow[i];
        we[2 * i] = w.x; we[2 * i + 1] = w.y;
    }

    const int n0 = blockIdx.x * kQewNPB;
    for (int i = nd; i < kQewNPB; i += 2) {
        const int n = n0 + i;
        if (n >= kN) break;
        const __half2* qrow = (const __half2*)&q16[(size_t)n * kHC + h * 32];
        float s = 0.f;
#pragma unroll
        for (int ii = 0; ii < 16; ii++) {
            const float2 qf = __half22float2(qrow[ii]);
            s = fmaf(qf.x, we[2 * ii], s);
            s = fmaf(qf.y, we[2 * ii + 1], s);
        }
        qeW[(size_t)n * kHC + o] = __float2half(s);
    }
}

// ---------------- qb[n,h] = sum_{c in h} q[n,c]*be[c] -----------------------
__global__ __launch_bounds__(256) void qb_kernel(
    const __half* __restrict__ q16, const float* __restrict__ be,
    float* __restrict__ qb)
{
    const int g = blockIdx.x * 256 + threadIdx.x;   // n*4 + h
    if (g >= kN * 4) return;
    const int n = g >> 2, h = g & 3;
    const __half2* qrow = (const __half2*)&q16[(size_t)n * kHC + h * 32];
    const float2* brow = (const float2*)&be[h * 32];
    float s = 0.f;
#pragma unroll
    for (int i = 0; i < 16; i++) {
        const float2 qf = __half22float2(qrow[i]);
        const float2 bf = brow[i];
        s = fmaf(qf.x, bf.x, s);
        s = fmaf(qf.y, bf.y, s);
    }
    qb[g] = s;
}

// ---------------- CSR build (once per call) ---------------------------------
__global__ __launch_bounds__(256) void hist_kernel(
    const int* __restrict__ dstI, int* __restrict__ deg)
{
    const int e = blockIdx.x * 256 + threadIdx.x;
    if (e < kE) atomicAdd(&deg[dstI[e]], 1);
}

__global__ __launch_bounds__(256) void scanA_kernel(
    const int* __restrict__ deg, int* __restrict__ locInc, int* __restrict__ blockSum)
{
    __shared__ int sm[256];
    const int t = threadIdx.x;
    const int i = blockIdx.x * 256 + t;
    sm[t] = (i < kN) ? deg[i] : 0;
    __syncthreads();
    for (int off = 1; off < 256; off <<= 1) {
        const int x = (t >= off) ? sm[t - off] : 0;
        __syncthreads();
        sm[t] += x;
        __syncthreads();
    }
    if (i < kN) locInc[i] = sm[t];
    if (t == 255) blockSum[blockIdx.x] = sm[255];
}

__global__ __launch_bounds__(256) void scanC_kernel(
    const int* __restrict__ deg, const int* __restrict__ locInc,
    const int* __restrict__ blockSum,
    int* __restrict__ rowptr, int* __restrict__ cursor)
{
    __shared__ int sm[256];
    const int t = threadIdx.x;
    const int b = blockIdx.x;
    sm[t] = (t < b) ? blockSum[t] : 0;   // b <= 195 < 256
    __syncthreads();
    for (int s = 128; s > 0; s >>= 1) {
        if (t < s) sm[t] += sm[t + s];
        __syncthreads();
    }
    const int off = sm[0];
    const int i = b * 256 + t;
    if (i < kN) {
        const int inc = locInc[i];
        const int excl = off + inc - deg[i];
        rowptr[i] = excl;
        cursor[i] = excl;
        if (i == kN - 1) rowptr[kN] = off + inc;
    }
}

__global__ __launch_bounds__(256) void scatter_kernel(
    const int* __restrict__ srcI, const int* __restrict__ dstI,
    int* __restrict__ cursor, int* __restrict__ esrc, int* __restrict__ eidx)
{
    const int e = blockIdx.x * 256 + threadIdx.x;
    if (e >= kE) return;
    const int d = dstI[e];
    const int pos = atomicAdd(&cursor[d], 1);
    esrc[pos] = srcI[e];
    eidx[pos] = e;
}

// ---------------- ea -> CSR-order fp16 copy (once per call) -----------------
__global__ __launch_bounds__(256) void ea_csr_kernel(
    const float* __restrict__ ea, const int* __restrict__ eidx,
    __half* __restrict__ eacsr)
{
    const int g = blockIdx.x * 256 + threadIdx.x;   // kE*16 threads
    if (g >= kE * 16) return;
    const int jj = g >> 4;
    const int li = g & 15;
    const int eid = eidx[jj];
    const float2 ea2 = *(const float2*)&ea[(size_t)eid * kED + 2 * li];
    *(__half2*)&eacsr[(size_t)jj * kED + 2 * li] = __floats2half2_rn(ea2.x, ea2.y);
}

// ---------------- Fused node pass: logits + softmax + agg + epilogue --------
// 128-thread blocks (2 waves = 2 nodes): less tail imbalance than 4-wave.
template<bool LAST>
__global__ __launch_bounds__(128) void node_kernel(
    const _Float16* __restrict__ q16, const __half* __restrict__ qeW,
    const float* __restrict__ qb, const _Float16* __restrict__ eacsr,
    const _Float16* __restrict__ kv16,
    const int* __restrict__ rowptr, const int* __restrict__ esrc,
    const _Float16* __restrict__ We16, const float* __restrict__ be,
    const __half* __restrict__ xr16, const float* __restrict__ Wb,
    const float* __restrict__ lnw, const float* __restrict__ lnb,
    void* __restrict__ hout)
{
    __shared__ __half wes[kED * kHC];   // 8 KB
    const int t = threadIdx.x;
    {
        float4* d4 = (float4*)wes;
        const float4* s4 = (const float4*)We16;
#pragma unroll
        for (int i = 0; i < 4; i++) d4[t + 128 * i] = s4[t + 128 * i];
    }
    __syncthreads();

    const int n = blockIdx.x * 2 + (t >> 6);   // kN % 2 == 0
    const int lane = t & 63;
    const int c = lane << 1;
    const int li = lane & 15;
    const int h = lane >> 4;

    const h2 qh  = *(const h2*)&q16[n * kHC + c];
    const h2 qwh = *(const h2*)((const _Float16*)qeW + n * kHC + c);
    const float qbv = qb[n * 4 + h];

    float acc0 = 0.f, acc1 = 0.f, t0 = 0.f, t1 = 0.f, den = 0.f;
    const int beg = rowptr[n], endp = rowptr[n + 1];
    const int lane4 = lane << 2;
    const _Float16* eap = eacsr + beg * kED + 2 * li;

    int jj = beg;
    // 4-edge unroll: 4 independent gather chains in flight
    for (; jj + 4 <= endp; jj += 4, eap += 4 * kED) {
        int s[4];
#pragma unroll
        for (int u = 0; u < 4; u++) s[u] = esrc[jj + u];
        half4 kv[4];
#pragma unroll
        for (int u = 0; u < 4; u++) kv[u] = *(const half4*)(kv16 + s[u] * 256 + lane4);
        h2 eav[4];
#pragma unroll
        for (int u = 0; u < 4; u++) eav[u] = *(const h2*)(eap + u * kED);
        float p[4];
#pragma unroll
        for (int u = 0; u < 4; u++) {
            const h2 kk = __builtin_shufflevector(kv[u], kv[u], 0, 1);
            p[u] = FDOT2(qh, kk, 0.f);
            p[u] = FDOT2(qwh, eav[u], p[u]);
        }
#pragma unroll
        for (int m = 1; m <= 8; m <<= 1) {
#pragma unroll
            for (int u = 0; u < 4; u++) p[u] += __shfl_xor(p[u], m);
        }
        float a[4];
#pragma unroll
        for (int u = 0; u < 4; u++) a[u] = __expf((p[u] + qbv) * RSQRT_C);
#pragma unroll
        for (int u = 0; u < 4; u++) {
            den += a[u];
            acc0 = fmaf((float)kv[u][2], a[u], acc0);
            acc1 = fmaf((float)kv[u][3], a[u], acc1);
            t0   = fmaf((float)eav[u][0], a[u], t0);
            t1   = fmaf((float)eav[u][1], a[u], t1);
        }
    }
    for (; jj < endp; jj++, eap += kED) {
        const int s0 = esrc[jj];
        const half4 kv0 = *(const half4*)(kv16 + s0 * 256 + lane4);
        const h2 ea0 = *(const h2*)eap;
        const h2 k0 = __builtin_shufflevector(kv0, kv0, 0, 1);
        float p0 = FDOT2(qh, k0, 0.f);
        p0 = FDOT2(qwh, ea0, p0);
        p0 += __shfl_xor(p0, 1);
        p0 += __shfl_xor(p0, 2);
        p0 += __shfl_xor(p0, 4);
        p0 += __shfl_xor(p0, 8);
        const float a0 = __expf((p0 + qbv) * RSQRT_C);
        den += a0;
        acc0 = fmaf((float)kv0[2], a0, acc0);
        acc1 = fmaf((float)kv0[3], a0, acc1);
        t0 = fmaf((float)ea0[0], a0, t0);
        t1 = fmaf((float)ea0[1], a0, t1);
    }
    const float invd = 1.f / (den + 1e-16f);
    float o0 = acc0 * invd;
    float o1 = acc1 * invd;
    const float tn0 = t0 * invd, tn1 = t1 * invd;
    const int gbase = lane & 48;
#pragma unroll
    for (int i = 0; i < 16; i++) {
        const float Ta = __shfl(tn0, gbase | i);
        const float Tb = __shfl(tn1, gbase | i);
        const float2 wa = __half22float2(*(const __half2*)&wes[(2 * i) * kHC + c]);
        const float2 wb = __half22float2(*(const __half2*)&wes[(2 * i + 1) * kHC + c]);
        o0 = fmaf(Ta, wa.x, o0); o1 = fmaf(Ta, wa.y, o1);
        o0 = fmaf(Tb, wb.x, o0); o1 = fmaf(Tb, wb.y, o1);
    }
    o0 += be[c];
    o1 += be[c + 1];

    const float2 r = __half22float2(*(const __half2*)&xr16[(size_t)n * kHC + c]);
    float z = o0 * Wb[c] + o1 * Wb[c + 1]
            + r.x * Wb[kHC + c] + r.y * Wb[kHC + c + 1]
            + (o0 - r.x) * Wb[2 * kHC + c] + (o1 - r.y) * Wb[2 * kHC + c + 1];
#pragma unroll
    for (int m = 1; m < 64; m <<= 1) z += __shfl_xor(z, m);
    const float beta = 1.f / (1.f + __expf(-z));

    const float g0 = beta * r.x + (1.f - beta) * o0;
    const float g1 = beta * r.y + (1.f - beta) * o1;

    float sm = g0 + g1;
    float sq = g0 * g0 + g1 * g1;
#pragma unroll
    for (int m = 1; m < 64; m <<= 1) {
        sm += __shfl_xor(sm, m);
        sq += __shfl_xor(sq, m);
    }
    const float mu  = sm * (1.f / kHC);
    const float var = sq * (1.f / kHC) - mu * mu;
    const float inv = rsqrtf(var + EPS_LN);

    float y0 = (g0 - mu) * inv * lnw[c] + lnb[c];
    float y1 = (g1 - mu) * inv * lnw[c + 1] + lnb[c + 1];
    y0 = y0 > 0.f ? y0 : NEG_SLOPE * y0;
    y1 = y1 > 0.f ? y1 : NEG_SLOPE * y1;
    if constexpr (LAST) {
        *(float2*)&((float*)hout)[(size_t)n * kHC + c] = make_float2(y0, y1);
    } else {
        *(__half2*)&((__half*)hout)[(size_t)n * kHC + c] = __floats2half2_rn(y0, y1);
    }
}

extern "C" void kernel_launch(void* const* d_in, const int* in_sizes, int n_in,
                              void* d_out, int out_size, void* d_ws, size_t ws_size,
                              hipStream_t stream)
{
    const float* x   = (const float*)d_in[0];
    const int*   ei  = (const int*)d_in[1];
    const float* ea  = (const float*)d_in[2];
    const float* Wq  = (const float*)d_in[3];
    const float* bq  = (const float*)d_in[4];
    const float* Wk  = (const float*)d_in[5];
    const float* bk  = (const float*)d_in[6];
    const float* Wv  = (const float*)d_in[7];
    const float* bv  = (const float*)d_in[8];
    const float* We  = (const float*)d_in[9];
    const float* be  = (const float*)d_in[10];
    const float* Wsk = (const float*)d_in[11];
    const float* bsk = (const float*)d_in[12];
    const float* Wb  = (const float*)d_in[13];
    const float* lnw = (const float*)d_in[14];
    const float* lnb = (const float*)d_in[15];
    float* out = (float*)d_out;

    const int* srcI = ei;
    const int* dstI = ei + kE;

    // ---- workspace layout (~100 MB) ----
    __half* q16  = (__half*)d_ws;
    __half* kv16 = q16 + (size_t)kN * kHC;              // [n][256] interleaved
    __half* qeW  = kv16 + (size_t)kN * 256;
    __half* xr16 = qeW + (size_t)kN * kHC;
    __half* h16  = xr16 + (size_t)kN * kHC;
    float*  qb   = (float*)(h16 + (size_t)kN * kHC);
    int* deg     = (int*)(qb + (size_t)kN * 4);
    int* rowptr  = deg + kN;
    int* cursor  = rowptr + kN + 1;
    int* esrc    = cursor + kN;
    int* eidx    = esrc + kE;
    __half* eacs = (__half*)(eidx + kE);
    _Float16* Wt = (_Float16*)(eacs + (size_t)kE * kED);   // 128 KB
    _Float16* We16 = Wt + 4 * 128 * 128;                   // 8 KB
    int* locInc  = (int*)(We16 + kED * kHC);
    int* blockSum = locInc + kN;

    // ---- CSR build (edge_index constant across layers) ----
    hipMemsetAsync(deg, 0, (size_t)kN * sizeof(int), stream);
    hist_kernel<<<(kE + 255) / 256, 256, 0, stream>>>(dstI, deg);
    scanA_kernel<<<kScanB, 256, 0, stream>>>(deg, locInc, blockSum);
    scanC_kernel<<<kScanB, 256, 0, stream>>>(deg, locInc, blockSum, rowptr, cursor);
    scatter_kernel<<<(kE + 255) / 256, 256, 0, stream>>>(srcI, dstI, cursor, esrc, eidx);
    ea_csr_kernel<<<(kE * 16 + 255) / 256, 256, 0, stream>>>(ea, eidx, eacs);

    for (int l = 0; l < kL; l++) {
        wt_kernel<<<32, 256, 0, stream>>>(
            Wq + (size_t)l * kHC * kHC, Wk + (size_t)l * kHC * kHC,
            Wv + (size_t)l * kHC * kHC, Wsk + (size_t)l * kHC * kHC, Wt);
        we16_kernel<<<16, 256, 0, stream>>>(We + (size_t)l * kHC * kED, We16);
        if (l == 0)
            proj_mfma_kernel<false><<<kProjBlocks, 256, 0, stream>>>(
                x, Wt,
                bq + (size_t)l * kHC, bk + (size_t)l * kHC,
                bv + (size_t)l * kHC, bsk + (size_t)l * kHC,
                (_Float16*)q16, (_Float16*)kv16, (_Float16*)xr16);
        else
            proj_mfma_kernel<true><<<kProjBlocks, 256, 0, stream>>>(
                h16, Wt,
                bq + (size_t)l * kHC, bk + (size_t)l * kHC,
                bv + (size_t)l * kHC, bsk + (size_t)l * kHC,
                (_Float16*)q16, (_Float16*)kv16, (_Float16*)xr16);
        qew_kernel<<<(kN + kQewNPB - 1) / kQewNPB, 256, 0, stream>>>(
            q16, We + (size_t)l * kED * kHC, qeW);
        qb_kernel<<<(kN * 4 + 255) / 256, 256, 0, stream>>>(
            q16, be + (size_t)l * kHC, qb);
        if (l == 0)
            node_kernel<false><<<kN / 2, 128, 0, stream>>>(
                (const _Float16*)q16, qeW, qb, (const _Float16*)eacs,
                (const _Float16*)kv16, rowptr, esrc,
                We16, be + (size_t)l * kHC,
                xr16, Wb + (size_t)l * 3 * kHC,
                lnw + (size_t)l * kHC, lnb + (size_t)l * kHC,
                h16);
        else
            node_kernel<true><<<kN / 2, 128, 0, stream>>>(
                (const _Float16*)q16, qeW, qb, (const _Float16*)eacs,
                (const _Float16*)kv16, rowptr, esrc,
                We16, be + (size_t)l * kHC,
                xr16, Wb + (size_t)l * 3 * kHC,
                lnw + (size_t)l * kHC, lnb + (size_t)l * kHC,
                out);
    }
}

// Round 18
// 305.664 us; speedup vs baseline: 1.0444x; 1.0292x over previous
//
#include <hip/hip_runtime.h>
#include <hip/hip_fp16.h>

constexpr int kN  = 50000;
constexpr int kE  = 400000;
constexpr int kHC = 128;
constexpr int kED = 32;
constexpr int kL  = 2;
constexpr int kScanB = (kN + 255) / 256;   // 196
constexpr int kProjBlocks = 512;           // persistent: 2 per CU
constexpr int kTiles = (kN + 31) / 32;     // 1563
constexpr int kKVB = 384;                  // bytes per kv row: 128 fp8 k + 256 fp16 v
#define EPS_LN 1e-5f
#define NEG_SLOPE 0.01f
#define RSQRT_C 0.17677669529663687f  // 1/sqrt(32)

using half8 = __attribute__((ext_vector_type(8))) _Float16;
using half4 = __attribute__((ext_vector_type(4))) _Float16;
using h2    = __attribute__((ext_vector_type(2))) _Float16;
using f32x4 = __attribute__((ext_vector_type(4))) float;

#if __has_builtin(__builtin_amdgcn_fdot2)
#define FDOT2(a, b, c) __builtin_amdgcn_fdot2((a), (b), (c), false)
#else
#define FDOT2(a, b, c) (fmaf((float)(a)[0], (float)(b)[0], \
                        fmaf((float)(a)[1], (float)(b)[1], (c))))
#endif

// ---------------- Weight transpose+convert: Wt[mat][n][k] fp16 --------------
__global__ __launch_bounds__(256) void wt_kernel(
    const float* __restrict__ Wq, const float* __restrict__ Wk,
    const float* __restrict__ Wv, const float* __restrict__ Ws,
    _Float16* __restrict__ Wt)
{
    const int g = blockIdx.x * 256 + threadIdx.x;   // 8192 total
    const int n  = g & 127;
    const int kc = (g >> 7) & 15;
    const int mat = g >> 11;
    const float* W = mat == 0 ? Wq : mat == 1 ? Wk : mat == 2 ? Wv : Ws;
    _Float16* dst = Wt + ((size_t)mat * 128 + n) * 128 + kc * 8;
#pragma unroll
    for (int i = 0; i < 8; i++) dst[i] = (_Float16)W[(kc * 8 + i) * kHC + n];
}

// ---------------- We -> fp16 copy (once per layer) --------------------------
__global__ __launch_bounds__(256) void we16_kernel(
    const float* __restrict__ We, _Float16* __restrict__ We16)
{
    const int g = blockIdx.x * 256 + threadIdx.x;   // 4096
    if (g < kED * kHC) We16[g] = (_Float16)We[g];
}

// ---------------- Persistent MFMA projection --------------------------------
// outputs: q16 [n][128], kv8 [n][384B] (k fp8 | v fp16), xr16 [n][128]
template<bool FP16IN>
__global__ __launch_bounds__(256, 2) void proj_mfma_kernel(
    const void* __restrict__ hin_, const _Float16* __restrict__ Wt,
    const float* __restrict__ bq, const float* __restrict__ bk,
    const float* __restrict__ bv, const float* __restrict__ bs,
    _Float16* __restrict__ q16, unsigned char* __restrict__ kv8,
    _Float16* __restrict__ xr16)
{
    __shared__ _Float16 lds_a[4096];          // [mt][ks][lane][8] frag-linear
    __shared__ _Float16 lds_o[4][32 * 132];   // repack staging, stride 132
    const int t = threadIdx.x;
    const int w = t >> 6;        // wave id = matrix id (0:q 1:k 2:v 3:skip)
    const int lane = t & 63;
    const int nrow = lane & 15;
    const int kc4  = (lane >> 4) * 4;

    half8 bf[32];
    {
        const _Float16* wtm = Wt + (size_t)w * 128 * 128;
#pragma unroll
        for (int ks = 0; ks < 4; ks++)
#pragma unroll
            for (int nt = 0; nt < 8; nt++)
                bf[ks * 8 + nt] = *(const half8*)
                    &wtm[(size_t)(nt * 16 + nrow) * 128 + ks * 32 + (lane >> 4) * 8];
    }

    const int sr  = t >> 3;
    const int sk0 = (t & 7) * 16;
    const int smt = sr >> 4;
    const int sl15 = sr & 15;

    float4 f[4];
    half8 hh[2];

    auto stage_to_regs = [&](int tile) {
        const int row = tile * 32 + sr;
        if (row < kN) {
            if constexpr (FP16IN) {
                const _Float16* src = (const _Float16*)hin_ + (size_t)row * kHC + sk0;
                hh[0] = *(const half8*)&src[0];
                hh[1] = *(const half8*)&src[8];
            } else {
                const float4* src = (const float4*)((const float*)hin_ + (size_t)row * kHC + sk0);
                f[0] = src[0]; f[1] = src[1]; f[2] = src[2]; f[3] = src[3];
            }
        } else {
            if constexpr (FP16IN) {
                hh[0] = half8{0, 0, 0, 0, 0, 0, 0, 0};
                hh[1] = half8{0, 0, 0, 0, 0, 0, 0, 0};
            } else {
                f[0] = f[1] = f[2] = f[3] = make_float4(0.f, 0.f, 0.f, 0.f);
            }
        }
    };

    auto regs_to_lds = [&]() {
        half8 h0, h1;
        if constexpr (FP16IN) {
            h0 = hh[0]; h1 = hh[1];
        } else {
            h0[0] = (_Float16)f[0].x; h0[1] = (_Float16)f[0].y;
            h0[2] = (_Float16)f[0].z; h0[3] = (_Float16)f[0].w;
            h0[4] = (_Float16)f[1].x; h0[5] = (_Float16)f[1].y;
            h0[6] = (_Float16)f[1].z; h0[7] = (_Float16)f[1].w;
            h1[0] = (_Float16)f[2].x; h1[1] = (_Float16)f[2].y;
            h1[2] = (_Float16)f[2].z; h1[3] = (_Float16)f[2].w;
            h1[4] = (_Float16)f[3].x; h1[5] = (_Float16)f[3].y;
            h1[6] = (_Float16)f[3].z; h1[7] = (_Float16)f[3].w;
        }
#pragma unroll
        for (int g = 0; g < 2; g++) {
            const int k  = sk0 + g * 8;
            const int ks = k >> 5;
            const int kc = (k >> 3) & 3;
            *(half8*)&lds_a[(((smt * 4 + ks) * 64) + kc * 16 + sl15) * 8] = g ? h1 : h0;
        }
    };

    const float* biasp = (w == 0) ? bq : (w == 1) ? bk : (w == 2) ? bv : bs;
    float bb[8];
#pragma unroll
    for (int nt = 0; nt < 8; nt++) bb[nt] = biasp[nt * 16 + nrow];

    int tile = blockIdx.x;
    stage_to_regs(tile);

    for (;;) {
        __syncthreads();
        regs_to_lds();
        __syncthreads();

        const int next = tile + kProjBlocks;
        const bool more = next < kTiles;
        if (more) stage_to_regs(next);

        f32x4 acc[2][8];
        const f32x4 z = {0.f, 0.f, 0.f, 0.f};
#pragma unroll
        for (int mt = 0; mt < 2; mt++)
#pragma unroll
            for (int nt = 0; nt < 8; nt++) acc[mt][nt] = z;

#pragma unroll
        for (int ks = 0; ks < 4; ks++) {
            const half8 a0 = *(const half8*)&lds_a[((0 * 4 + ks) * 64 + lane) * 8];
            const half8 a1 = *(const half8*)&lds_a[((1 * 4 + ks) * 64 + lane) * 8];
#pragma unroll
            for (int nt = 0; nt < 8; nt++) {
                acc[0][nt] = __builtin_amdgcn_mfma_f32_16x16x32_f16(a0, bf[ks * 8 + nt], acc[0][nt], 0, 0, 0);
                acc[1][nt] = __builtin_amdgcn_mfma_f32_16x16x32_f16(a1, bf[ks * 8 + nt], acc[1][nt], 0, 0, 0);
            }
        }

#pragma unroll
        for (int nt = 0; nt < 8; nt++) {
#pragma unroll
            for (int mt = 0; mt < 2; mt++)
#pragma unroll
                for (int r = 0; r < 4; r++)
                    lds_o[w][(mt * 16 + kc4 + r) * 132 + nt * 16 + nrow] =
                        (_Float16)(acc[mt][nt][r] + bb[nt]);
        }
        __syncthreads();

        const int grow = tile * 32 + sr;
        if (grow < kN) {
            {   // q
                const _Float16* s = &lds_o[0][sr * 132 + sk0];
                _Float16* d = q16 + (size_t)grow * kHC + sk0;
#pragma unroll
                for (int i = 0; i < 4; i++)
                    *(half4*)&d[i * 4] = *(const half4*)&s[i * 4];
            }
            {   // k fp8: row bytes [0,128), channel i at byte i
                const _Float16* sk = &lds_o[1][sr * 132 + sk0];
                unsigned int w4[4];
#pragma unroll
                for (int p = 0; p < 4; p++) {
                    unsigned int wd = 0;
                    wd = __builtin_amdgcn_cvt_pk_fp8_f32(
                        (float)sk[4 * p], (float)sk[4 * p + 1], wd, false);
                    wd = __builtin_amdgcn_cvt_pk_fp8_f32(
                        (float)sk[4 * p + 2], (float)sk[4 * p + 3], wd, true);
                    w4[p] = wd;
                }
                *(uint4*)(kv8 + (size_t)grow * kKVB + sk0) =
                    make_uint4(w4[0], w4[1], w4[2], w4[3]);
            }
            {   // v fp16: row bytes [128,384), channel i at 128 + 2i
                const _Float16* sv = &lds_o[2][sr * 132 + sk0];
                _Float16* d = (_Float16*)(kv8 + (size_t)grow * kKVB + 128) + sk0;
                *(half8*)&d[0] = *(const half8*)&sv[0];
                *(half8*)&d[8] = *(const half8*)&sv[8];
            }
            {   // xr
                const _Float16* s = &lds_o[3][sr * 132 + sk0];
                _Float16* d = xr16 + (size_t)grow * kHC + sk0;
#pragma unroll
                for (int i = 0; i < 4; i++)
                    *(half4*)&d[i * 4] = *(const half4*)&s[i * 4];
            }
        }

        if (!more) break;
        tile = next;
    }
}

// ---------------- qeW: register-blocked, 32 nodes per block -----------------
constexpr int kQewNPB = 32;
__global__ __launch_bounds__(256) void qew_kernel(
    const __half* __restrict__ q16, const float* __restrict__ We,
    __half* __restrict__ qeW)
{
    const int t = threadIdx.x;
    const int o = t & 127;       // output index = h*32 + j
    const int h = o >> 5;
    const int j = o & 31;
    const int nd = t >> 7;

    float we[32];
    const float2* wrow = (const float2*)&We[j * kHC + h * 32];
#pragma unroll
    for (int i = 0; i < 16; i++) {
        const float2 w = wrow[i];
        we[2 * i] = w.x; we[2 * i + 1] = w.y;
    }

    const int n0 = blockIdx.x * kQewNPB;
    for (int i = nd; i < kQewNPB; i += 2) {
        const int n = n0 + i;
        if (n >= kN) break;
        const __half2* qrow = (const __half2*)&q16[(size_t)n * kHC + h * 32];
        float s = 0.f;
#pragma unroll
        for (int ii = 0; ii < 16; ii++) {
            const float2 qf = __half22float2(qrow[ii]);
            s = fmaf(qf.x, we[2 * ii], s);
            s = fmaf(qf.y, we[2 * ii + 1], s);
        }
        qeW[(size_t)n * kHC + o] = __float2half(s);
    }
}

// ---------------- qb[n,h] = sum_{c in h} q[n,c]*be[c] -----------------------
__global__ __launch_bounds__(256) void qb_kernel(
    const __half* __restrict__ q16, const float* __restrict__ be,
    float* __restrict__ qb)
{
    const int g = blockIdx.x * 256 + threadIdx.x;   // n*4 + h
    if (g >= kN * 4) return;
    const int n = g >> 2, h = g & 3;
    const __half2* qrow = (const __half2*)&q16[(size_t)n * kHC + h * 32];
    const float2* brow = (const float2*)&be[h * 32];
    float s = 0.f;
#pragma unroll
    for (int i = 0; i < 16; i++) {
        const float2 qf = __half22float2(qrow[i]);
        const float2 bf = brow[i];
        s = fmaf(qf.x, bf.x, s);
        s = fmaf(qf.y, bf.y, s);
    }
    qb[g] = s;
}

// ---------------- CSR build (once per call) ---------------------------------
__global__ __launch_bounds__(256) void hist_kernel(
    const int* __restrict__ dstI, int* __restrict__ deg)
{
    const int e = blockIdx.x * 256 + threadIdx.x;
    if (e < kE) atomicAdd(&deg[dstI[e]], 1);
}

__global__ __launch_bounds__(256) void scanA_kernel(
    const int* __restrict__ deg, int* __restrict__ locInc, int* __restrict__ blockSum)
{
    __shared__ int sm[256];
    const int t = threadIdx.x;
    const int i = blockIdx.x * 256 + t;
    sm[t] = (i < kN) ? deg[i] : 0;
    __syncthreads();
    for (int off = 1; off < 256; off <<= 1) {
        const int x = (t >= off) ? sm[t - off] : 0;
        __syncthreads();
        sm[t] += x;
        __syncthreads();
    }
    if (i < kN) locInc[i] = sm[t];
    if (t == 255) blockSum[blockIdx.x] = sm[255];
}

__global__ __launch_bounds__(256) void scanC_kernel(
    const int* __restrict__ deg, const int* __restrict__ locInc,
    const int* __restrict__ blockSum,
    int* __restrict__ rowptr, int* __restrict__ cursor)
{
    __shared__ int sm[256];
    const int t = threadIdx.x;
    const int b = blockIdx.x;
    sm[t] = (t < b) ? blockSum[t] : 0;   // b <= 195 < 256
    __syncthreads();
    for (int s = 128; s > 0; s >>= 1) {
        if (t < s) sm[t] += sm[t + s];
        __syncthreads();
    }
    const int off = sm[0];
    const int i = b * 256 + t;
    if (i < kN) {
        const int inc = locInc[i];
        const int excl = off + inc - deg[i];
        rowptr[i] = excl;
        cursor[i] = excl;
        if (i == kN - 1) rowptr[kN] = off + inc;
    }
}

__global__ __launch_bounds__(256) void scatter_kernel(
    const int* __restrict__ srcI, const int* __restrict__ dstI,
    int* __restrict__ cursor, int* __restrict__ esrc, int* __restrict__ eidx)
{
    const int e = blockIdx.x * 256 + threadIdx.x;
    if (e >= kE) return;
    const int d = dstI[e];
    const int pos = atomicAdd(&cursor[d], 1);
    esrc[pos] = srcI[e];
    eidx[pos] = e;
}

// ---------------- ea -> CSR-order fp16 copy (once per call) -----------------
__global__ __launch_bounds__(256) void ea_csr_kernel(
    const float* __restrict__ ea, const int* __restrict__ eidx,
    __half* __restrict__ eacsr)
{
    const int g = blockIdx.x * 256 + threadIdx.x;   // kE*16 threads
    if (g >= kE * 16) return;
    const int jj = g >> 4;
    const int li = g & 15;
    const int eid = eidx[jj];
    const float2 ea2 = *(const float2*)&ea[(size_t)eid * kED + 2 * li];
    *(__half2*)&eacsr[(size_t)jj * kED + 2 * li] = __floats2half2_rn(ea2.x, ea2.y);
}

// ---------------- Fused node pass: logits + softmax + agg + epilogue --------
template<bool LAST>
__global__ __launch_bounds__(128) void node_kernel(
    const _Float16* __restrict__ q16, const __half* __restrict__ qeW,
    const float* __restrict__ qb, const _Float16* __restrict__ eacsr,
    const unsigned char* __restrict__ kv8,
    const int* __restrict__ rowptr, const int* __restrict__ esrc,
    const _Float16* __restrict__ We16, const float* __restrict__ be,
    const __half* __restrict__ xr16, const float* __restrict__ Wb,
    const float* __restrict__ lnw, const float* __restrict__ lnb,
    void* __restrict__ hout)
{
    __shared__ __half wes[kED * kHC];   // 8 KB
    const int t = threadIdx.x;
    {
        float4* d4 = (float4*)wes;
        const float4* s4 = (const float4*)We16;
#pragma unroll
        for (int i = 0; i < 4; i++) d4[t + 128 * i] = s4[t + 128 * i];
    }
    __syncthreads();

    const int n = blockIdx.x * 2 + (t >> 6);   // kN % 2 == 0
    const int lane = t & 63;
    const int c = lane << 1;
    const int li = lane & 15;
    const int h = lane >> 4;

    const h2 qh  = *(const h2*)&q16[n * kHC + c];
    const h2 qwh = *(const h2*)((const _Float16*)qeW + n * kHC + c);
    const float qf0 = (float)qh[0], qf1 = (float)qh[1];
    const float qbv = qb[n * 4 + h];

    float acc0 = 0.f, acc1 = 0.f, t0 = 0.f, t1 = 0.f, den = 0.f;
    const int beg = rowptr[n], endp = rowptr[n + 1];
    const int kOff = lane << 1;          // k fp8: 2 bytes at byte 2*lane
    const int vOff = 128 + (lane << 2);  // v fp16: 4 bytes at 128 + 4*lane
    const _Float16* eap = eacsr + beg * kED + 2 * li;

    int jj = beg;
    // 4-edge unroll: 4 independent gather chains in flight
    for (; jj + 4 <= endp; jj += 4, eap += 4 * kED) {
        int s[4];
#pragma unroll
        for (int u = 0; u < 4; u++) s[u] = esrc[jj + u];
        unsigned int kw[4];
        h2 vv[4];
#pragma unroll
        for (int u = 0; u < 4; u++) {
            const unsigned char* row = kv8 + (size_t)s[u] * kKVB;
            kw[u] = *(const unsigned short*)(row + kOff);
            vv[u] = *(const h2*)(row + vOff);
        }
        h2 eav[4];
#pragma unroll
        for (int u = 0; u < 4; u++) eav[u] = *(const h2*)(eap + u * kED);
        float p[4];
#pragma unroll
        for (int u = 0; u < 4; u++) {
            const float k0 = __builtin_amdgcn_cvt_f32_fp8(kw[u], 0);
            const float k1 = __builtin_amdgcn_cvt_f32_fp8(kw[u], 1);
            p[u] = fmaf(qf0, k0, qf1 * k1);
            p[u] = FDOT2(qwh, eav[u], p[u]);
        }
#pragma unroll
        for (int m = 1; m <= 8; m <<= 1) {
#pragma unroll
            for (int u = 0; u < 4; u++) p[u] += __shfl_xor(p[u], m);
        }
        float a[4];
#pragma unroll
        for (int u = 0; u < 4; u++) a[u] = __expf((p[u] + qbv) * RSQRT_C);
#pragma unroll
        for (int u = 0; u < 4; u++) {
            den += a[u];
            acc0 = fmaf((float)vv[u][0], a[u], acc0);
            acc1 = fmaf((float)vv[u][1], a[u], acc1);
            t0   = fmaf((float)eav[u][0], a[u], t0);
            t1   = fmaf((float)eav[u][1], a[u], t1);
        }
    }
    for (; jj < endp; jj++, eap += kED) {
        const int s0 = esrc[jj];
        const unsigned char* row = kv8 + (size_t)s0 * kKVB;
        const unsigned int kw = *(const unsigned short*)(row + kOff);
        const h2 vv = *(const h2*)(row + vOff);
        const h2 ea0 = *(const h2*)eap;
        const float k0 = __builtin_amdgcn_cvt_f32_fp8(kw, 0);
        const float k1 = __builtin_amdgcn_cvt_f32_fp8(kw, 1);
        float p0 = fmaf(qf0, k0, qf1 * k1);
        p0 = FDOT2(qwh, ea0, p0);
        p0 += __shfl_xor(p0, 1);
        p0 += __shfl_xor(p0, 2);
        p0 += __shfl_xor(p0, 4);
        p0 += __shfl_xor(p0, 8);
        const float a0 = __expf((p0 + qbv) * RSQRT_C);
        den += a0;
        acc0 = fmaf((float)vv[0], a0, acc0);
        acc1 = fmaf((float)vv[1], a0, acc1);
        t0 = fmaf((float)ea0[0], a0, t0);
        t1 = fmaf((float)ea0[1], a0, t1);
    }
    const float invd = 1.f / (den + 1e-16f);
    float o0 = acc0 * invd;
    float o1 = acc1 * invd;
    const float tn0 = t0 * invd, tn1 = t1 * invd;
    const int gbase = lane & 48;
#pragma unroll
    for (int i = 0; i < 16; i++) {
        const float Ta = __shfl(tn0, gbase | i);
        const float Tb = __shfl(tn1, gbase | i);
        const float2 wa = __half22float2(*(const __half2*)&wes[(2 * i) * kHC + c]);
        const float2 wb = __half22float2(*(const __half2*)&wes[(2 * i + 1) * kHC + c]);
        o0 = fmaf(Ta, wa.x, o0); o1 = fmaf(Ta, wa.y, o1);
        o0 = fmaf(Tb, wb.x, o0); o1 = fmaf(Tb, wb.y, o1);
    }
    o0 += be[c];
    o1 += be[c + 1];

    const float2 r = __half22float2(*(const __half2*)&xr16[(size_t)n * kHC + c]);
    float z = o0 * Wb[c] + o1 * Wb[c + 1]
            + r.x * Wb[kHC + c] + r.y * Wb[kHC + c + 1]
            + (o0 - r.x) * Wb[2 * kHC + c] + (o1 - r.y) * Wb[2 * kHC + c + 1];
#pragma unroll
    for (int m = 1; m < 64; m <<= 1) z += __shfl_xor(z, m);
    const float beta = 1.f / (1.f + __expf(-z));

    const float g0 = beta * r.x + (1.f - beta) * o0;
    const float g1 = beta * r.y + (1.f - beta) * o1;

    float sm = g0 + g1;
    float sq = g0 * g0 + g1 * g1;
#pragma unroll
    for (int m = 1; m < 64; m <<= 1) {
        sm += __shfl_xor(sm, m);
        sq += __shfl_xor(sq, m);
    }
    const float mu  = sm * (1.f / kHC);
    const float var = sq * (1.f / kHC) - mu * mu;
    const float inv = rsqrtf(var + EPS_LN);

    float y0 = (g0 - mu) * inv * lnw[c] + lnb[c];
    float y1 = (g1 - mu) * inv * lnw[c + 1] + lnb[c + 1];
    y0 = y0 > 0.f ? y0 : NEG_SLOPE * y0;
    y1 = y1 > 0.f ? y1 : NEG_SLOPE * y1;
    if constexpr (LAST) {
        *(float2*)&((float*)hout)[(size_t)n * kHC + c] = make_float2(y0, y1);
    } else {
        *(__half2*)&((__half*)hout)[(size_t)n * kHC + c] = __floats2half2_rn(y0, y1);
    }
}

extern "C" void kernel_launch(void* const* d_in, const int* in_sizes, int n_in,
                              void* d_out, int out_size, void* d_ws, size_t ws_size,
                              hipStream_t stream)
{
    const float* x   = (const float*)d_in[0];
    const int*   ei  = (const int*)d_in[1];
    const float* ea  = (const float*)d_in[2];
    const float* Wq  = (const float*)d_in[3];
    const float* bq  = (const float*)d_in[4];
    const float* Wk  = (const float*)d_in[5];
    const float* bk  = (const float*)d_in[6];
    const float* Wv  = (const float*)d_in[7];
    const float* bv  = (const float*)d_in[8];
    const float* We  = (const float*)d_in[9];
    const float* be  = (const float*)d_in[10];
    const float* Wsk = (const float*)d_in[11];
    const float* bsk = (const float*)d_in[12];
    const float* Wb  = (const float*)d_in[13];
    const float* lnw = (const float*)d_in[14];
    const float* lnb = (const float*)d_in[15];
    float* out = (float*)d_out;

    const int* srcI = ei;
    const int* dstI = ei + kE;

    // ---- workspace layout (~95 MB) ----
    __half* q16  = (__half*)d_ws;
    unsigned char* kv8 = (unsigned char*)(q16 + (size_t)kN * kHC);  // [n][384B]
    __half* qeW  = (__half*)(kv8 + (size_t)kN * kKVB);
    __half* xr16 = qeW + (size_t)kN * kHC;
    __half* h16  = xr16 + (size_t)kN * kHC;
    float*  qb   = (float*)(h16 + (size_t)kN * kHC);
    int* deg     = (int*)(qb + (size_t)kN * 4);
    int* rowptr  = deg + kN;
    int* cursor  = rowptr + kN + 1;
    int* esrc    = cursor + kN;
    int* eidx    = esrc + kE;
    __half* eacs = (__half*)(eidx + kE);
    _Float16* Wt = (_Float16*)(eacs + (size_t)kE * kED);   // 128 KB
    _Float16* We16 = Wt + 4 * 128 * 128;                   // 8 KB
    int* locInc  = (int*)(We16 + kED * kHC);
    int* blockSum = locInc + kN;

    // ---- CSR build (edge_index constant across layers) ----
    hipMemsetAsync(deg, 0, (size_t)kN * sizeof(int), stream);
    hist_kernel<<<(kE + 255) / 256, 256, 0, stream>>>(dstI, deg);
    scanA_kernel<<<kScanB, 256, 0, stream>>>(deg, locInc, blockSum);
    scanC_kernel<<<kScanB, 256, 0, stream>>>(deg, locInc, blockSum, rowptr, cursor);
    scatter_kernel<<<(kE + 255) / 256, 256, 0, stream>>>(srcI, dstI, cursor, esrc, eidx);
    ea_csr_kernel<<<(kE * 16 + 255) / 256, 256, 0, stream>>>(ea, eidx, eacs);

    for (int l = 0; l < kL; l++) {
        wt_kernel<<<32, 256, 0, stream>>>(
            Wq + (size_t)l * kHC * kHC, Wk + (size_t)l * kHC * kHC,
            Wv + (size_t)l * kHC * kHC, Wsk + (size_t)l * kHC * kHC, Wt);
        we16_kernel<<<16, 256, 0, stream>>>(We + (size_t)l * kHC * kED, We16);
        if (l == 0)
            proj_mfma_kernel<false><<<kProjBlocks, 256, 0, stream>>>(
                x, Wt,
                bq + (size_t)l * kHC, bk + (size_t)l * kHC,
                bv + (size_t)l * kHC, bsk + (size_t)l * kHC,
                (_Float16*)q16, kv8, (_Float16*)xr16);
        else
            proj_mfma_kernel<true><<<kProjBlocks, 256, 0, stream>>>(
                h16, Wt,
                bq + (size_t)l * kHC, bk + (size_t)l * kHC,
                bv + (size_t)l * kHC, bsk + (size_t)l * kHC,
                (_Float16*)q16, kv8, (_Float16*)xr16);
        qew_kernel<<<(kN + kQewNPB - 1) / kQewNPB, 256, 0, stream>>>(
            q16, We + (size_t)l * kED * kHC, qeW);
        qb_kernel<<<(kN * 4 + 255) / 256, 256, 0, stream>>>(
            q16, be + (size_t)l * kHC, qb);
        if (l == 0)
            node_kernel<false><<<kN / 2, 128, 0, stream>>>(
                (const _Float16*)q16, qeW, qb, (const _Float16*)eacs,
                kv8, rowptr, esrc,
                We16, be + (size_t)l * kHC,
                xr16, Wb + (size_t)l * 3 * kHC,
                lnw + (size_t)l * kHC, lnb + (size_t)l * kHC,
                h16);
        else
            node_kernel<true><<<kN / 2, 128, 0, stream>>>(
                (const _Float16*)q16, qeW, qb, (const _Float16*)eacs,
                kv8, rowptr, esrc,
                We16, be + (size_t)l * kHC,
                xr16, Wb + (size_t)l * 3 * kHC,
                lnw + (size_t)l * kHC, lnb + (size_t)l * kHC,
                out);
    }
}